// Round 2
// baseline (314.020 us; speedup 1.0000x reference)
//
#include <hip/hip_runtime.h>
#include <math.h>

#define D        64
#define QBLK     32
#define KBLK     64
#define NTHR     128
#define RELCLIP  16
#define NEGBIG   -1.0e9f
// NEG(1e9) / scale(8) for the padding-mask additive term
#define MASKNEG_SCALED 1.25e8f

// LDS layouts (floats):
//  QsT[d][r]  : 64 x 36 (pad for bank spread; Q pre-scaled by 1/8)
//  KsT[d][c]  : 64 x 68 (stride 68 -> float4-aligned rows, 2-way banks only)
//  Vs [c][d]  : 64 x 68
//  PsT[c][r]  : 64 x 36
//  drel[r][t] : 32 x 33 (pre-scaled rel-key dots for this q-tile)
//  krel staged temporarily inside KsT space before the main loop.

__global__ __launch_bounds__(NTHR, 2)
void attn_rel_kernel(const float* __restrict__ Q,
                     const float* __restrict__ K,
                     const float* __restrict__ V,
                     const float* __restrict__ Msk,
                     const float* __restrict__ Krel,
                     const float* __restrict__ Vrel,
                     float* __restrict__ Out,
                     int B, int L)
{
    __shared__ float QsT[64][36];
    __shared__ float KsT[64][68];
    __shared__ float Vs [64][68];
    __shared__ float PsT[64][36];
    __shared__ float drel[32][33];

    const int tid = threadIdx.x;
    const int b   = blockIdx.y;
    const int q0  = blockIdx.x * QBLK;

    const int r0 = (tid >> 4) << 2;   // 0..28, 4 rows per thread
    const int c0 = (tid & 15) << 2;   // 0..60, 4 cols per thread (also d0 in PV)

    // ---- stage Q (scaled by 1/8) transposed ----
    const float* Qb = Q + ((size_t)b * L + q0) * D;
    #pragma unroll
    for (int rep = 0; rep < 4; ++rep) {              // 512 float4
        int v = tid + rep * NTHR;
        int r = v >> 4;
        int dq = (v & 15) << 2;
        float4 t4 = *(const float4*)&Qb[r * D + dq];
        QsT[dq + 0][r] = t4.x * 0.125f;
        QsT[dq + 1][r] = t4.y * 0.125f;
        QsT[dq + 2][r] = t4.z * 0.125f;
        QsT[dq + 3][r] = t4.w * 0.125f;
    }

    // ---- stage key_relative into (not-yet-used) KsT space: krel[t][d], stride 68 ----
    float (*krel)[68] = (float (*)[68])KsT;
    for (int v = tid; v < 33 * 16; v += NTHR) {      // 528 float4
        int row = v >> 4;
        int dd = (v & 15) << 2;
        *(float4*)&krel[row][dd] = *(const float4*)&Krel[row * D + dd];
    }
    __syncthreads();

    // ---- dot_rel[r][t] = (Q[q0+r]/8) . key_relative[t] ----
    for (int e = tid; e < QBLK * 33; e += NTHR) {
        int r = e / 33;
        int t = e - r * 33;
        float acc = 0.f;
        #pragma unroll 8
        for (int d = 0; d < D; ++d)
            acc = fmaf(QsT[d][r], krel[t][d], acc);
        drel[r][t] = acc;
    }

    // ---- online softmax state ----
    float o[4][4];
    float mprev[4], lsum[4];
    #pragma unroll
    for (int i = 0; i < 4; ++i) {
        mprev[i] = -1.0e30f;
        lsum[i] = 0.f;
        #pragma unroll
        for (int j = 0; j < 4; ++j) o[i][j] = 0.f;
    }

    const int kmax = (q0 + QBLK - 1) >> 6;           // inclusive k-tile bound
    const float* Kbase = K + (size_t)b * L * D;
    const float* Vbase = V + (size_t)b * L * D;
    const float* Mbase = Msk + (size_t)b * L;

    for (int kt = 0; kt <= kmax; ++kt) {
        const int k0 = kt * KBLK;
        __syncthreads();   // prior PV done; safe to overwrite KsT/Vs

        // ---- stage K transposed + V natural ----
        #pragma unroll
        for (int rep = 0; rep < 8; ++rep) {          // 1024 float4
            int v = tid + rep * NTHR;
            int c = v >> 4;
            int dk = (v & 15) << 2;
            float4 t4 = *(const float4*)&Kbase[(size_t)(k0 + c) * D + dk];
            KsT[dk + 0][c] = t4.x;
            KsT[dk + 1][c] = t4.y;
            KsT[dk + 2][c] = t4.z;
            KsT[dk + 3][c] = t4.w;
        }
        #pragma unroll
        for (int rep = 0; rep < 8; ++rep) {
            int v = tid + rep * NTHR;
            int c = v >> 4;
            int dk = (v & 15) << 2;
            *(float4*)&Vs[c][dk] =
                *(const float4*)&Vbase[(size_t)(k0 + c) * D + dk];
        }
        __syncthreads();

        // ---- S = (Q/8) K^T  (4x4 register tile) ----
        float s[4][4];
        #pragma unroll
        for (int i = 0; i < 4; ++i)
            #pragma unroll
            for (int j = 0; j < 4; ++j) s[i][j] = 0.f;

        #pragma unroll 4
        for (int d = 0; d < D; ++d) {
            const float4 a4 = *(const float4*)&QsT[d][r0];
            const float4 b4 = *(const float4*)&KsT[d][c0];
            const float a[4] = {a4.x, a4.y, a4.z, a4.w};
            const float bb[4] = {b4.x, b4.y, b4.z, b4.w};
            #pragma unroll
            for (int i = 0; i < 4; ++i)
                #pragma unroll
                for (int j = 0; j < 4; ++j)
                    s[i][j] = fmaf(a[i], bb[j], s[i][j]);
        }

        // ---- bias + masks ----
        const bool near = (k0 + KBLK - 1 + RELCLIP >= q0);
        float mk[4];
        #pragma unroll
        for (int j = 0; j < 4; ++j) mk[j] = Mbase[k0 + c0 + j];

        if (near) {
            #pragma unroll
            for (int i = 0; i < 4; ++i) {
                const int qq = q0 + r0 + i;
                #pragma unroll
                for (int j = 0; j < 4; ++j) {
                    const int kk = k0 + c0 + j;
                    const int dlt = qq - kk;
                    if (dlt < 0) {
                        s[i][j] = NEGBIG;
                    } else {
                        int idx = dlt + RELCLIP;
                        if (idx > 2 * RELCLIP) idx = 2 * RELCLIP;
                        s[i][j] += drel[r0 + i][idx]
                                 + (mk[j] - 1.f) * MASKNEG_SCALED;
                    }
                }
            }
        } else {
            #pragma unroll
            for (int i = 0; i < 4; ++i) {
                const float b32 = drel[r0 + i][2 * RELCLIP];
                #pragma unroll
                for (int j = 0; j < 4; ++j)
                    s[i][j] += b32 + (mk[j] - 1.f) * MASKNEG_SCALED;
            }
        }

        // ---- online softmax (rows owned by 16 lanes tx of same wave group) ----
        float mt[4], mnew[4], f[4], rs[4];
        #pragma unroll
        for (int i = 0; i < 4; ++i) {
            mt[i] = fmaxf(fmaxf(s[i][0], s[i][1]), fmaxf(s[i][2], s[i][3]));
        }
        #pragma unroll
        for (int off = 1; off < 16; off <<= 1)
            #pragma unroll
            for (int i = 0; i < 4; ++i)
                mt[i] = fmaxf(mt[i], __shfl_xor(mt[i], off, 64));

        #pragma unroll
        for (int i = 0; i < 4; ++i) {
            mnew[i] = fmaxf(mprev[i], mt[i]);
            f[i] = __expf(mprev[i] - mnew[i]);
            rs[i] = 0.f;
            #pragma unroll
            for (int j = 0; j < 4; ++j) {
                s[i][j] = __expf(s[i][j] - mnew[i]);
                rs[i] += s[i][j];
            }
        }
        #pragma unroll
        for (int off = 1; off < 16; off <<= 1)
            #pragma unroll
            for (int i = 0; i < 4; ++i)
                rs[i] += __shfl_xor(rs[i], off, 64);

        #pragma unroll
        for (int i = 0; i < 4; ++i) {
            lsum[i] = lsum[i] * f[i] + rs[i];
            mprev[i] = mnew[i];
            #pragma unroll
            for (int j = 0; j < 4; ++j) {
                o[i][j] *= f[i];
                PsT[c0 + j][r0 + i] = s[i][j];
            }
        }
        __syncthreads();

        // ---- PV + near-diagonal relative-value recombination ----
        if (near) {
            for (int c = 0; c < KBLK; ++c) {
                const float4 p4 = *(const float4*)&PsT[c][r0];
                const float4 v4 = *(const float4*)&Vs[c][c0];
                const float p[4] = {p4.x, p4.y, p4.z, p4.w};
                #pragma unroll
                for (int i = 0; i < 4; ++i) {
                    o[i][0] = fmaf(p[i], v4.x, o[i][0]);
                    o[i][1] = fmaf(p[i], v4.y, o[i][1]);
                    o[i][2] = fmaf(p[i], v4.z, o[i][2]);
                    o[i][3] = fmaf(p[i], v4.w, o[i][3]);
                    const int dlt = (q0 + r0 + i) - (k0 + c);
                    if (dlt >= 0 && dlt <= RELCLIP) {
                        const float4 vr = *(const float4*)
                            &Vrel[(size_t)(RELCLIP - dlt) * D + c0];
                        o[i][0] = fmaf(p[i], vr.x, o[i][0]);
                        o[i][1] = fmaf(p[i], vr.y, o[i][1]);
                        o[i][2] = fmaf(p[i], vr.z, o[i][2]);
                        o[i][3] = fmaf(p[i], vr.w, o[i][3]);
                    }
                }
            }
        } else {
            #pragma unroll 4
            for (int c = 0; c < KBLK; ++c) {
                const float4 p4 = *(const float4*)&PsT[c][r0];
                const float4 v4 = *(const float4*)&Vs[c][c0];
                const float p[4] = {p4.x, p4.y, p4.z, p4.w};
                #pragma unroll
                for (int i = 0; i < 4; ++i) {
                    o[i][0] = fmaf(p[i], v4.x, o[i][0]);
                    o[i][1] = fmaf(p[i], v4.y, o[i][1]);
                    o[i][2] = fmaf(p[i], v4.z, o[i][2]);
                    o[i][3] = fmaf(p[i], v4.w, o[i][3]);
                }
            }
        }
    }

    // ---- finalize: divide by softmax denom, write out ----
    #pragma unroll
    for (int i = 0; i < 4; ++i) {
        const float inv = 1.f / lsum[i];
        float4 res;
        res.x = o[i][0] * inv;
        res.y = o[i][1] * inv;
        res.z = o[i][2] * inv;
        res.w = o[i][3] * inv;
        *(float4*)&Out[((size_t)b * L + (q0 + r0 + i)) * D + c0] = res;
    }
}

extern "C" void kernel_launch(void* const* d_in, const int* in_sizes, int n_in,
                              void* d_out, int out_size, void* d_ws, size_t ws_size,
                              hipStream_t stream) {
    const float* Q    = (const float*)d_in[0];
    const float* K    = (const float*)d_in[1];
    const float* V    = (const float*)d_in[2];
    const float* Msk  = (const float*)d_in[3];
    const float* Krel = (const float*)d_in[4];
    const float* Vrel = (const float*)d_in[5];
    float* Out = (float*)d_out;

    const int B = 8, L = 2048;
    dim3 grid(L / QBLK, B);
    dim3 block(NTHR);
    attn_rel_kernel<<<grid, block, 0, stream>>>(Q, K, V, Msk, Krel, Vrel, Out, B, L);
}

// Round 5
// 103.538 us; speedup vs baseline: 3.0329x; 3.0329x over previous
//
#include <hip/hip_runtime.h>

typedef __attribute__((ext_vector_type(4))) float f32x4;
typedef __attribute__((ext_vector_type(8))) short s16x8;
typedef __attribute__((ext_vector_type(4))) short s16x4;

#define LSEQ 2048
#define NB   8
#define CH   8            // k-tiles (of 64) per split-K chunk
#define UPB  80           // work units per batch
#define NUNIT 640

// workspace byte offsets
#define OFF_QB    0x000000u   // bf16 [8][2048][64]  (Q pre-scaled by 1/8)
#define OFF_KB    0x200000u   // bf16 [8][2048][64]
#define OFF_VTB   0x400000u   // bf16 [8][64][2048]  (V transposed)
#define OFF_PEN   0x600000u   // f32  [8][2048]      ((mask-1)*1.25e8)
#define OFF_KREL  0x610000u   // bf16 [48][64]       (rows>=33 zero)
#define OFF_OPART 0x620000u   // f32  [640][64][64]
#define OFF_ML    0x1020000u  // f32  [640][64][2]

__device__ __forceinline__ unsigned short f2bf(float f) {
    union { float f; unsigned int u; } v; v.f = f;
    unsigned int u = v.u;
    return (unsigned short)((u + 0x7fffu + ((u >> 16) & 1u)) >> 16);
}

__device__ __forceinline__ float bf2f(unsigned short b) {
    union { unsigned int u; float f; } v; v.u = ((unsigned int)b) << 16;
    return v.f;
}

// ---------------- convert / transpose pre-pass ----------------
__global__ __launch_bounds__(256)
void convert_kernel(const float* __restrict__ Q, const float* __restrict__ K,
                    const float* __restrict__ V, const float* __restrict__ Msk,
                    const float* __restrict__ Krel, char* __restrict__ ws)
{
    const int tid = threadIdx.x;
    const int bid = blockIdx.x;
    unsigned short* Qb  = (unsigned short*)(ws + OFF_QB);
    unsigned short* Kb  = (unsigned short*)(ws + OFF_KB);
    unsigned short* VTb = (unsigned short*)(ws + OFF_VTB);
    float*          pen = (float*)(ws + OFF_PEN);
    unsigned short* Krb = (unsigned short*)(ws + OFF_KREL);

    if (bid < 1024) {                       // Q -> bf16, scaled 1/8
        int base = bid * 1024 + tid * 4;
        f32x4 q4 = *(const f32x4*)(Q + base);
        s16x4 o;
        o.x = (short)f2bf(q4.x * 0.125f); o.y = (short)f2bf(q4.y * 0.125f);
        o.z = (short)f2bf(q4.z * 0.125f); o.w = (short)f2bf(q4.w * 0.125f);
        *(s16x4*)(Qb + base) = o;
    } else if (bid < 2048) {                // K -> bf16
        int base = (bid - 1024) * 1024 + tid * 4;
        f32x4 k4 = *(const f32x4*)(K + base);
        s16x4 o;
        o.x = (short)f2bf(k4.x); o.y = (short)f2bf(k4.y);
        o.z = (short)f2bf(k4.z); o.w = (short)f2bf(k4.w);
        *(s16x4*)(Kb + base) = o;
    } else if (bid < 2304) {                // V transpose (64x64 tiles) -> bf16
        __shared__ unsigned short tileT[64][72];   // stride 72 => 16B-aligned rows
        int tile = bid - 2048;
        int b = tile >> 5, k0 = (tile & 31) << 6;
        #pragma unroll
        for (int rep = 0; rep < 4; ++rep) {
            int idx = tid + rep * 256;              // 0..1023
            int kr = idx >> 4, dc0 = (idx & 15) << 2;
            f32x4 v4 = *(const f32x4*)(V + (size_t)(b * 2048 + k0 + kr) * 64 + dc0);
            tileT[dc0 + 0][kr] = f2bf(v4.x);
            tileT[dc0 + 1][kr] = f2bf(v4.y);
            tileT[dc0 + 2][kr] = f2bf(v4.z);
            tileT[dc0 + 3][kr] = f2bf(v4.w);
        }
        __syncthreads();
        #pragma unroll
        for (int rep = 0; rep < 2; ++rep) {
            int idx = tid + rep * 256;              // 0..511
            int d = idx >> 3, ch = idx & 7;
            *(s16x8*)(VTb + (size_t)(b * 64 + d) * 2048 + k0 + ch * 8) =
                *(const s16x8*)&tileT[d][ch * 8];
        }
    } else if (bid < 2312) {                // mask -> additive penalty
        int i0 = (bid - 2304) * 2048 + tid * 8;
        f32x4 m0 = *(const f32x4*)(Msk + i0);
        f32x4 m1 = *(const f32x4*)(Msk + i0 + 4);
        f32x4 p0 = (m0 - 1.0f) * 1.25e8f;
        f32x4 p1 = (m1 - 1.0f) * 1.25e8f;
        *(f32x4*)(pen + i0) = p0;
        *(f32x4*)(pen + i0 + 4) = p1;
    } else {                                // Krel -> bf16, padded to 48 rows
        for (int g = tid; g < 768; g += 256) {
            int e = g * 4, row = e >> 6, col = e & 63;
            s16x4 o;
            if (row < 33) {
                f32x4 v = *(const f32x4*)(Krel + row * 64 + col);
                o.x = (short)f2bf(v.x); o.y = (short)f2bf(v.y);
                o.z = (short)f2bf(v.z); o.w = (short)f2bf(v.w);
            } else {
                o.x = 0; o.y = 0; o.z = 0; o.w = 0;
            }
            *(s16x4*)(Krb + row * 64 + col) = o;
        }
    }
}

// ---------------- main flash-attention (split-K) ----------------
#define LDS_KS   0          // bf16 K-tile  [64 rows][128B], XOR-swizzled
#define LDS_VT   8192       // bf16 V^T-tile[64 rows][128B], XOR-swizzled
#define LDS_P    16384      // per-wave P  (4 x 2048B), XOR-swizzled
#define LDS_DREL 24576      // f32 [4][16][20]
#define LDS_VREL 29696      // f32 [17][72]
#define LDS_TOT  34592

__device__ __forceinline__ void near_bias(f32x4& sv, const f32x4& pv, int cc,
                                          int k0, int g0, int q,
                                          const float* drel) {
#pragma unroll
    for (int r = 0; r < 4; ++r) {
        int kk = k0 + cc * 16 + 4 * g0 + r;
        int dlt = q - kk;
        int idx = dlt < 16 ? dlt : 16;
        idx = idx < 0 ? 0 : idx;
        float bb = drel[idx];
        float v = sv[r] + bb + pv[r];
        sv[r] = (dlt < 0) ? -1e30f : v;
    }
}

__global__ __launch_bounds__(256, 3)
void attn_main(const float* __restrict__ Vrel_g, float* __restrict__ Out,
               char* __restrict__ ws)
{
    __shared__ __align__(16) char lds[LDS_TOT];
    const int tid  = threadIdx.x;
    const int wv   = tid >> 6;
    const int lane = tid & 63;
    const int g0   = lane >> 4;
    const int qh   = lane & 15;

    // decode split-K unit
    int u = blockIdx.x;
    int b = u / UPB;
    int u2 = u - b * UPB;
    int t, chunk, nck;
    if (u2 < 8)       { t = u2;               chunk = 0;          nck = 1; }
    else if (u2 < 24) { t = 8  + (u2 - 8) / 2;  chunk = (u2 - 8) & 1;  nck = 2; }
    else if (u2 < 48) { t = 16 + (u2 - 24) / 3; chunk = (u2 - 24) % 3; nck = 3; }
    else              { t = 24 + (u2 - 48) / 4; chunk = (u2 - 48) & 3; nck = 4; }
    const int q0   = t << 6;
    const int q0w  = q0 + wv * 16;
    const int q    = q0w + qh;
    const int ck0  = chunk * CH;
    const int ckend = min(ck0 + CH, t + 1);
    const bool is_final = (nck == 1);

    const unsigned short* Qb  = (const unsigned short*)(ws + OFF_QB);
    const unsigned short* Kb  = (const unsigned short*)(ws + OFF_KB);
    const unsigned short* VTb = (const unsigned short*)(ws + OFF_VTB);
    const float*          pen = (const float*)(ws + OFF_PEN);
    const unsigned short* Krb = (const unsigned short*)(ws + OFF_KREL);

    // Q fragments (hoisted for entire kernel); q-row = lane&15
    const size_t qrow = (size_t)(b * 2048 + q) * 64;
    s16x8 qf0 = *(const s16x8*)(Qb + qrow + 0 * 32 + g0 * 8);
    s16x8 qf1 = *(const s16x8*)(Qb + qrow + 1 * 32 + g0 * 8);

    // drel (relative-key dots) via MFMA: Krel rows 16..31 and 32
    {
        s16x8 a10 = *(const s16x8*)(Krb + (16 + qh) * 64 + 0 * 32 + g0 * 8);
        s16x8 a11 = *(const s16x8*)(Krb + (16 + qh) * 64 + 1 * 32 + g0 * 8);
        s16x8 a20 = *(const s16x8*)(Krb + (32 + qh) * 64 + 0 * 32 + g0 * 8);
        s16x8 a21 = *(const s16x8*)(Krb + (32 + qh) * 64 + 1 * 32 + g0 * 8);
        f32x4 z = {0.f, 0.f, 0.f, 0.f};
        f32x4 d1 = __builtin_amdgcn_mfma_f32_16x16x32_bf16(a10, qf0, z, 0, 0, 0);
        d1 = __builtin_amdgcn_mfma_f32_16x16x32_bf16(a11, qf1, d1, 0, 0, 0);
        f32x4 d2 = __builtin_amdgcn_mfma_f32_16x16x32_bf16(a20, qf0, z, 0, 0, 0);
        d2 = __builtin_amdgcn_mfma_f32_16x16x32_bf16(a21, qf1, d2, 0, 0, 0);
        float* drel = (float*)(lds + LDS_DREL) + wv * 320 + qh * 20;
        drel[4 * g0 + 0] = d1.x; drel[4 * g0 + 1] = d1.y;
        drel[4 * g0 + 2] = d1.z; drel[4 * g0 + 3] = d1.w;
        if (g0 == 0) drel[16] = d2.x;     // drel[q][32]
    }
    asm volatile("" ::: "memory");        // order drel writes vs reads below
    const float* drelT = (const float*)(lds + LDS_DREL) + wv * 320 + qh * 20;
    float bias32 = drelT[16];             // same-wave LDS readback

    // Vrel rows 0..16 staged f32 (stride 72 -> 16B-aligned rows)
    {
        float* vr = (float*)(lds + LDS_VREL);
        for (int i = tid; i < 17 * 16; i += 256) {
            int row = i >> 4, c4 = (i & 15) << 2;
            *(f32x4*)(vr + row * 72 + c4) = *(const f32x4*)(Vrel_g + row * 64 + c4);
        }
    }

    f32x4 o0 = {0,0,0,0}, o1 = {0,0,0,0}, o2 = {0,0,0,0}, o3 = {0,0,0,0};
    float mprev = -1e30f, lsum = 0.f;

    char* KsL = lds + LDS_KS;
    char* VtL = lds + LDS_VT;
    char* PL  = lds + LDS_P + wv * 2048;
    const int swzq = (qh & 7) << 4;
    const float* vrel = (const float*)(lds + LDS_VREL);

    for (int kt = ck0; kt < ckend; ++kt) {
        const int k0 = kt << 6;
        __syncthreads();   // prior PV done; safe to overwrite KsL/VtL
        // stage K tile + V^T tile (bf16, 8KB each), XOR-swizzled writes
        #pragma unroll
        for (int rep = 0; rep < 2; ++rep) {
            int idx = tid + rep * 256;              // 0..511
            int row = idx >> 3, cb = (idx & 7) << 4;
            int sw = cb ^ ((row & 7) << 4);
            *(s16x8*)(KsL + row * 128 + sw) =
                *(const s16x8*)((const char*)(Kb + (size_t)(b * 2048 + k0 + row) * 64) + cb);
            *(s16x8*)(VtL + row * 128 + sw) =
                *(const s16x8*)((const char*)(VTb + (size_t)(b * 64 + row) * 2048 + k0) + cb);
        }
        __syncthreads();

        if (k0 <= q0w + 15) {
            // ---- S^T = K_tile . Q^T  (4 chunks of 16 keys, d split 2x32) ----
            f32x4 s0, s1, s2, s3;
            {
                f32x4 z = {0,0,0,0};
                const int b0 = (16 * g0) ^ swzq;
                const int b1 = (64 + 16 * g0) ^ swzq;
                s16x8 a00 = *(const s16x8*)(KsL + (0  + qh) * 128 + b0);
                s16x8 a01 = *(const s16x8*)(KsL + (0  + qh) * 128 + b1);
                s16x8 a10 = *(const s16x8*)(KsL + (16 + qh) * 128 + b0);
                s16x8 a11 = *(const s16x8*)(KsL + (16 + qh) * 128 + b1);
                s16x8 a20 = *(const s16x8*)(KsL + (32 + qh) * 128 + b0);
                s16x8 a21 = *(const s16x8*)(KsL + (32 + qh) * 128 + b1);
                s16x8 a30 = *(const s16x8*)(KsL + (48 + qh) * 128 + b0);
                s16x8 a31 = *(const s16x8*)(KsL + (48 + qh) * 128 + b1);
                s0 = __builtin_amdgcn_mfma_f32_16x16x32_bf16(a00, qf0, z, 0, 0, 0);
                s0 = __builtin_amdgcn_mfma_f32_16x16x32_bf16(a01, qf1, s0, 0, 0, 0);
                s1 = __builtin_amdgcn_mfma_f32_16x16x32_bf16(a10, qf0, z, 0, 0, 0);
                s1 = __builtin_amdgcn_mfma_f32_16x16x32_bf16(a11, qf1, s1, 0, 0, 0);
                s2 = __builtin_amdgcn_mfma_f32_16x16x32_bf16(a20, qf0, z, 0, 0, 0);
                s2 = __builtin_amdgcn_mfma_f32_16x16x32_bf16(a21, qf1, s2, 0, 0, 0);
                s3 = __builtin_amdgcn_mfma_f32_16x16x32_bf16(a30, qf0, z, 0, 0, 0);
                s3 = __builtin_amdgcn_mfma_f32_16x16x32_bf16(a31, qf1, s3, 0, 0, 0);
            }
            // ---- bias + mask penalty ----
            const float* penb = pen + b * 2048 + k0 + 4 * g0;
            f32x4 pn0 = *(const f32x4*)(penb + 0);
            f32x4 pn1 = *(const f32x4*)(penb + 16);
            f32x4 pn2 = *(const f32x4*)(penb + 32);
            f32x4 pn3 = *(const f32x4*)(penb + 48);
            const bool near = (k0 + 79 >= q0w);
            if (!near) {
                s0 += pn0 + bias32; s1 += pn1 + bias32;
                s2 += pn2 + bias32; s3 += pn3 + bias32;
            } else {
                near_bias(s0, pn0, 0, k0, g0, q, drelT);
                near_bias(s1, pn1, 1, k0, g0, q, drelT);
                near_bias(s2, pn2, 2, k0, g0, q, drelT);
                near_bias(s3, pn3, 3, k0, g0, q, drelT);
            }
            // ---- online softmax (row q = lanes {qh, qh+16, qh+32, qh+48}) ----
            float mt = fmaxf(fmaxf(fmaxf(s0.x, s0.y), fmaxf(s0.z, s0.w)),
                      fmaxf(fmaxf(fmaxf(s1.x, s1.y), fmaxf(s1.z, s1.w)),
                      fmaxf(fmaxf(fmaxf(s2.x, s2.y), fmaxf(s2.z, s2.w)),
                            fmaxf(fmaxf(s3.x, s3.y), fmaxf(s3.z, s3.w)))));
            mt = fmaxf(mt, __shfl_xor(mt, 16));
            mt = fmaxf(mt, __shfl_xor(mt, 32));
            float mnew = fmaxf(mprev, mt);
            float fsc = __expf(mprev - mnew);
            s0.x = __expf(s0.x - mnew); s0.y = __expf(s0.y - mnew);
            s0.z = __expf(s0.z - mnew); s0.w = __expf(s0.w - mnew);
            s1.x = __expf(s1.x - mnew); s1.y = __expf(s1.y - mnew);
            s1.z = __expf(s1.z - mnew); s1.w = __expf(s1.w - mnew);
            s2.x = __expf(s2.x - mnew); s2.y = __expf(s2.y - mnew);
            s2.z = __expf(s2.z - mnew); s2.w = __expf(s2.w - mnew);
            s3.x = __expf(s3.x - mnew); s3.y = __expf(s3.y - mnew);
            s3.z = __expf(s3.z - mnew); s3.w = __expf(s3.w - mnew);
            float rs = (s0.x + s0.y + s0.z + s0.w) + (s1.x + s1.y + s1.z + s1.w)
                     + (s2.x + s2.y + s2.z + s2.w) + (s3.x + s3.y + s3.z + s3.w);
            rs += __shfl_xor(rs, 16);
            rs += __shfl_xor(rs, 32);
            lsum = lsum * fsc + rs;
            mprev = mnew;
            o0 *= fsc; o1 *= fsc; o2 *= fsc; o3 *= fsc;

            // ---- P -> bf16 -> per-wave LDS (swizzled, short-typed stores) ----
            {
                s16x4 pk;
                pk.x = (short)f2bf(s0.x); pk.y = (short)f2bf(s0.y);
                pk.z = (short)f2bf(s0.z); pk.w = (short)f2bf(s0.w);
                *(s16x4*)(PL + qh * 128 + ((0  + 8 * g0) ^ swzq)) = pk;
                pk.x = (short)f2bf(s1.x); pk.y = (short)f2bf(s1.y);
                pk.z = (short)f2bf(s1.z); pk.w = (short)f2bf(s1.w);
                *(s16x4*)(PL + qh * 128 + ((32 + 8 * g0) ^ swzq)) = pk;
                pk.x = (short)f2bf(s2.x); pk.y = (short)f2bf(s2.y);
                pk.z = (short)f2bf(s2.z); pk.w = (short)f2bf(s2.w);
                *(s16x4*)(PL + qh * 128 + ((64 + 8 * g0) ^ swzq)) = pk;
                pk.x = (short)f2bf(s3.x); pk.y = (short)f2bf(s3.y);
                pk.z = (short)f2bf(s3.z); pk.w = (short)f2bf(s3.w);
                *(s16x4*)(PL + qh * 128 + ((96 + 8 * g0) ^ swzq)) = pk;
            }
            // Compiler fence: P stores must precede the P reads below.
            asm volatile("" ::: "memory");
            // ---- O^T += V^T . P^T ----
            {
                const int b0 = (16 * g0) ^ swzq;
                const int b1 = (64 + 16 * g0) ^ swzq;
                s16x8 bP0 = *(const s16x8*)(PL + qh * 128 + b0);
                s16x8 bP1 = *(const s16x8*)(PL + qh * 128 + b1);
                asm volatile("" ::: "memory");
                s16x8 v00 = *(const s16x8*)(VtL + (0  + qh) * 128 + b0);
                s16x8 v01 = *(const s16x8*)(VtL + (0  + qh) * 128 + b1);
                s16x8 v10 = *(const s16x8*)(VtL + (16 + qh) * 128 + b0);
                s16x8 v11 = *(const s16x8*)(VtL + (16 + qh) * 128 + b1);
                s16x8 v20 = *(const s16x8*)(VtL + (32 + qh) * 128 + b0);
                s16x8 v21 = *(const s16x8*)(VtL + (32 + qh) * 128 + b1);
                s16x8 v30 = *(const s16x8*)(VtL + (48 + qh) * 128 + b0);
                s16x8 v31 = *(const s16x8*)(VtL + (48 + qh) * 128 + b1);
                o0 = __builtin_amdgcn_mfma_f32_16x16x32_bf16(v00, bP0, o0, 0, 0, 0);
                o0 = __builtin_amdgcn_mfma_f32_16x16x32_bf16(v01, bP1, o0, 0, 0, 0);
                o1 = __builtin_amdgcn_mfma_f32_16x16x32_bf16(v10, bP0, o1, 0, 0, 0);
                o1 = __builtin_amdgcn_mfma_f32_16x16x32_bf16(v11, bP1, o1, 0, 0, 0);
                o2 = __builtin_amdgcn_mfma_f32_16x16x32_bf16(v20, bP0, o2, 0, 0, 0);
                o2 = __builtin_amdgcn_mfma_f32_16x16x32_bf16(v21, bP1, o2, 0, 0, 0);
                o3 = __builtin_amdgcn_mfma_f32_16x16x32_bf16(v30, bP0, o3, 0, 0, 0);
                o3 = __builtin_amdgcn_mfma_f32_16x16x32_bf16(v31, bP1, o3, 0, 0, 0);
            }
            // ---- near-diagonal relative-value recombination ----
            // O^T[d][q] += P[q][kk] * Vrel[16-(q-kk)][d] for ALL d; P read
            // from the per-wave P LDS (key->all-d broadcast; 4 lanes with the
            // same qh read the same address = free LDS broadcast).
            if (near) {
                const int kql = q - k0;
                #pragma unroll
                for (int dlt = 0; dlt <= 16; ++dlt) {
                    int kkl = kql - dlt;
                    if (kkl >= 0 && kkl < 64) {
                        float p = bf2f(*(const unsigned short*)
                                       (PL + qh * 128 + ((2 * kkl) ^ swzq)));
                        const float* vrow = vrel + (16 - dlt) * 72 + 4 * g0;
                        o0 += p * *(const f32x4*)(vrow + 0);
                        o1 += p * *(const f32x4*)(vrow + 16);
                        o2 += p * *(const f32x4*)(vrow + 32);
                        o3 += p * *(const f32x4*)(vrow + 48);
                    }
                }
            }
        }
    }

    // ---- epilogue ----
    if (is_final) {
        float inv = 1.f / lsum;
        float* op = Out + (size_t)(b * 2048 + q) * 64 + 4 * g0;
        *(f32x4*)(op + 0)  = o0 * inv;
        *(f32x4*)(op + 16) = o1 * inv;
        *(f32x4*)(op + 32) = o2 * inv;
        *(f32x4*)(op + 48) = o3 * inv;
    } else {
        float* op = (float*)(ws + OFF_OPART) + (size_t)u * 4096 + (wv * 16 + qh) * 64 + 4 * g0;
        *(f32x4*)(op + 0)  = o0;
        *(f32x4*)(op + 16) = o1;
        *(f32x4*)(op + 32) = o2;
        *(f32x4*)(op + 48) = o3;
        if (g0 == 0) {
            float* ml = (float*)(ws + OFF_ML) + (size_t)u * 128 + (wv * 16 + qh) * 2;
            ml[0] = mprev; ml[1] = lsum;
        }
    }
}

// ---------------- split-K combine ----------------
__global__ __launch_bounds__(256)
void combine_kernel(float* __restrict__ Out, const char* __restrict__ ws)
{
    int bid = blockIdx.x;          // 192 = 8 batches x 24 q-tiles (t=8..31)
    int b = bid / 24;
    int t = 8 + bid % 24;
    int nck = t / 8 + 1;
    int S;
    if (t < 16)      S = 8 + 2 * (t - 8);
    else if (t < 24) S = 24 + 3 * (t - 16);
    else             S = 48 + 4 * (t - 24);
    int ubase = b * UPB + S;
    int tid = threadIdx.x;
    int qloc = tid >> 2;
    int d0 = (tid & 3) << 4;
    const float* mlb = (const float*)(ws + OFF_ML);
    const float* opb = (const float*)(ws + OFF_OPART);

    float m[4], l[4];
    float M = -1e30f;
    #pragma unroll
    for (int i = 0; i < 4; ++i) {
        if (i < nck) {
            const float* ml = mlb + (size_t)(ubase + i) * 128 + qloc * 2;
            m[i] = ml[0]; l[i] = ml[1];
            M = fmaxf(M, m[i]);
        }
    }
    float L = 0.f;
    float coef[4];
    #pragma unroll
    for (int i = 0; i < 4; ++i) {
        if (i < nck) { coef[i] = __expf(m[i] - M); L += l[i] * coef[i]; }
    }
    f32x4 a0 = {0,0,0,0}, a1 = {0,0,0,0}, a2 = {0,0,0,0}, a3 = {0,0,0,0};
    #pragma unroll
    for (int i = 0; i < 4; ++i) {
        if (i < nck) {
            const float* op = opb + (size_t)(ubase + i) * 4096 + qloc * 64 + d0;
            a0 += coef[i] * *(const f32x4*)(op + 0);
            a1 += coef[i] * *(const f32x4*)(op + 4);
            a2 += coef[i] * *(const f32x4*)(op + 8);
            a3 += coef[i] * *(const f32x4*)(op + 12);
        }
    }
    float inv = 1.f / L;
    float* oo = Out + (size_t)(b * 2048 + t * 64 + qloc) * 64 + d0;
    *(f32x4*)(oo + 0)  = a0 * inv;
    *(f32x4*)(oo + 4)  = a1 * inv;
    *(f32x4*)(oo + 8)  = a2 * inv;
    *(f32x4*)(oo + 12) = a3 * inv;
}

extern "C" void kernel_launch(void* const* d_in, const int* in_sizes, int n_in,
                              void* d_out, int out_size, void* d_ws, size_t ws_size,
                              hipStream_t stream) {
    (void)in_sizes; (void)n_in; (void)out_size; (void)ws_size;
    const float* Q    = (const float*)d_in[0];
    const float* K    = (const float*)d_in[1];
    const float* V    = (const float*)d_in[2];
    const float* Msk  = (const float*)d_in[3];
    const float* Krel = (const float*)d_in[4];
    const float* Vrel = (const float*)d_in[5];
    float* Out = (float*)d_out;
    char* ws = (char*)d_ws;

    convert_kernel<<<2313, 256, 0, stream>>>(Q, K, V, Msk, Krel, ws);
    attn_main<<<NUNIT, 256, 0, stream>>>(Vrel, Out, ws);
    combine_kernel<<<192, 256, 0, stream>>>(Out, ws);
}

// Round 6
// 102.768 us; speedup vs baseline: 3.0556x; 1.0075x over previous
//
#include <hip/hip_runtime.h>

typedef __attribute__((ext_vector_type(4))) float f32x4;
typedef __attribute__((ext_vector_type(8))) short s16x8;
typedef __attribute__((ext_vector_type(4))) short s16x4;

#define LSEQ 2048
#define NB   8
#define CH   8            // k-tiles (of 64) per split-K chunk
#define UPB  80           // work units per batch
#define NUNIT 640

// log2(e) folded into Q scale and mask-penalty scale: softmax runs in the
// log2 domain (exp2 is the native v_exp_f32; probabilities identical).
#define QSCALE   0.180336880f    // 0.125 * log2(e)
#define PENSCALE 1.8033688e8f    // 1.25e8 * log2(e)

// workspace byte offsets
#define OFF_QB    0x000000u   // bf16 [8][2048][64]  (Q pre-scaled by QSCALE)
#define OFF_KB    0x200000u   // bf16 [8][2048][64]
#define OFF_VTB   0x400000u   // bf16 [8][64][2048]  (V transposed)
#define OFF_PEN   0x600000u   // f32  [8][2048]      ((mask-1)*PENSCALE)
#define OFF_KREL  0x610000u   // bf16 [48][64]       (rows>=33 zero)
#define OFF_OPART 0x620000u   // f32  [640][64][64]
#define OFF_ML    0x1020000u  // f32  [640][64][2]

__device__ __forceinline__ unsigned short f2bf(float f) {
    union { float f; unsigned int u; } v; v.f = f;
    unsigned int u = v.u;
    return (unsigned short)((u + 0x7fffu + ((u >> 16) & 1u)) >> 16);
}

__device__ __forceinline__ float bf2f(unsigned short b) {
    union { unsigned int u; float f; } v; v.u = ((unsigned int)b) << 16;
    return v.f;
}

// ---------------- convert / transpose pre-pass ----------------
__global__ __launch_bounds__(256)
void convert_kernel(const float* __restrict__ Q, const float* __restrict__ K,
                    const float* __restrict__ V, const float* __restrict__ Msk,
                    const float* __restrict__ Krel, char* __restrict__ ws)
{
    const int tid = threadIdx.x;
    const int bid = blockIdx.x;
    unsigned short* Qb  = (unsigned short*)(ws + OFF_QB);
    unsigned short* Kb  = (unsigned short*)(ws + OFF_KB);
    unsigned short* VTb = (unsigned short*)(ws + OFF_VTB);
    float*          pen = (float*)(ws + OFF_PEN);
    unsigned short* Krb = (unsigned short*)(ws + OFF_KREL);

    if (bid < 1024) {                       // Q -> bf16, scaled
        int base = bid * 1024 + tid * 4;
        f32x4 q4 = *(const f32x4*)(Q + base);
        s16x4 o;
        o.x = (short)f2bf(q4.x * QSCALE); o.y = (short)f2bf(q4.y * QSCALE);
        o.z = (short)f2bf(q4.z * QSCALE); o.w = (short)f2bf(q4.w * QSCALE);
        *(s16x4*)(Qb + base) = o;
    } else if (bid < 2048) {                // K -> bf16
        int base = (bid - 1024) * 1024 + tid * 4;
        f32x4 k4 = *(const f32x4*)(K + base);
        s16x4 o;
        o.x = (short)f2bf(k4.x); o.y = (short)f2bf(k4.y);
        o.z = (short)f2bf(k4.z); o.w = (short)f2bf(k4.w);
        *(s16x4*)(Kb + base) = o;
    } else if (bid < 2304) {                // V transpose (64x64 tiles) -> bf16
        __shared__ unsigned short tileT[64][72];   // stride 72 => 16B-aligned rows
        int tile = bid - 2048;
        int b = tile >> 5, k0 = (tile & 31) << 6;
        #pragma unroll
        for (int rep = 0; rep < 4; ++rep) {
            int idx = tid + rep * 256;              // 0..1023
            int kr = idx >> 4, dc0 = (idx & 15) << 2;
            f32x4 v4 = *(const f32x4*)(V + (size_t)(b * 2048 + k0 + kr) * 64 + dc0);
            tileT[dc0 + 0][kr] = f2bf(v4.x);
            tileT[dc0 + 1][kr] = f2bf(v4.y);
            tileT[dc0 + 2][kr] = f2bf(v4.z);
            tileT[dc0 + 3][kr] = f2bf(v4.w);
        }
        __syncthreads();
        #pragma unroll
        for (int rep = 0; rep < 2; ++rep) {
            int idx = tid + rep * 256;              // 0..511
            int d = idx >> 3, ch = idx & 7;
            *(s16x8*)(VTb + (size_t)(b * 64 + d) * 2048 + k0 + ch * 8) =
                *(const s16x8*)&tileT[d][ch * 8];
        }
    } else if (bid < 2312) {                // mask -> additive penalty (log2 dom)
        int i0 = (bid - 2304) * 2048 + tid * 8;
        f32x4 m0 = *(const f32x4*)(Msk + i0);
        f32x4 m1 = *(const f32x4*)(Msk + i0 + 4);
        f32x4 p0 = (m0 - 1.0f) * PENSCALE;
        f32x4 p1 = (m1 - 1.0f) * PENSCALE;
        *(f32x4*)(pen + i0) = p0;
        *(f32x4*)(pen + i0 + 4) = p1;
    } else {                                // Krel -> bf16, padded to 48 rows
        for (int g = tid; g < 768; g += 256) {
            int e = g * 4, row = e >> 6, col = e & 63;
            s16x4 o;
            if (row < 33) {
                f32x4 v = *(const f32x4*)(Krel + row * 64 + col);
                o.x = (short)f2bf(v.x); o.y = (short)f2bf(v.y);
                o.z = (short)f2bf(v.z); o.w = (short)f2bf(v.w);
            } else {
                o.x = 0; o.y = 0; o.z = 0; o.w = 0;
            }
            *(s16x4*)(Krb + row * 64 + col) = o;
        }
    }
}

// ---------------- main flash-attention (split-K, double-buffered) ----------------
// LDS map (bytes):
#define LDS_BUF0 0          // K: 0-8191, VT: 8192-16383  (XOR-swizzled rows)
#define LDS_BUF1 16384      // second ping-pong buffer
#define LDS_P    32768      // per-wave P (4 x 2048B), XOR-swizzled
#define LDS_DREL 40960      // f32 [4][16][20]
#define LDS_VREL 46080      // f32 [17][72]
#define LDS_TOT  50976

__device__ __forceinline__ void near_bias(f32x4& sv, const f32x4& pv, int cc,
                                          int k0, int g0, int q,
                                          const float* drel) {
#pragma unroll
    for (int r = 0; r < 4; ++r) {
        int kk = k0 + cc * 16 + 4 * g0 + r;
        int dlt = q - kk;
        int idx = dlt < 16 ? dlt : 16;
        idx = idx < 0 ? 0 : idx;
        float bb = drel[idx];
        float v = sv[r] + bb + pv[r];
        sv[r] = (dlt < 0) ? -1e30f : v;
    }
}

__global__ __launch_bounds__(256, 3)
void attn_main(const float* __restrict__ Vrel_g, float* __restrict__ Out,
               char* __restrict__ ws)
{
    __shared__ __align__(16) char lds[LDS_TOT];
    const int tid  = threadIdx.x;
    const int wv   = tid >> 6;
    const int lane = tid & 63;
    const int g0   = lane >> 4;
    const int qh   = lane & 15;

    // decode split-K unit
    int u = blockIdx.x;
    int b = u / UPB;
    int u2 = u - b * UPB;
    int t, chunk, nck;
    if (u2 < 8)       { t = u2;               chunk = 0;          nck = 1; }
    else if (u2 < 24) { t = 8  + (u2 - 8) / 2;  chunk = (u2 - 8) & 1;  nck = 2; }
    else if (u2 < 48) { t = 16 + (u2 - 24) / 3; chunk = (u2 - 24) % 3; nck = 3; }
    else              { t = 24 + (u2 - 48) / 4; chunk = (u2 - 48) & 3; nck = 4; }
    const int q0   = t << 6;
    const int q0w  = q0 + wv * 16;
    const int q    = q0w + qh;
    const int ck0  = chunk * CH;
    const int ckend = min(ck0 + CH, t + 1);
    const bool is_final = (nck == 1);

    const unsigned short* Qb  = (const unsigned short*)(ws + OFF_QB);
    const unsigned short* Kb  = (const unsigned short*)(ws + OFF_KB);
    const unsigned short* VTb = (const unsigned short*)(ws + OFF_VTB);
    const float*          pen = (const float*)(ws + OFF_PEN);
    const unsigned short* Krb = (const unsigned short*)(ws + OFF_KREL);

    // Q fragments (hoisted); q-row = lane&15
    const size_t qrow = (size_t)(b * 2048 + q) * 64;
    s16x8 qf0 = *(const s16x8*)(Qb + qrow + 0 * 32 + g0 * 8);
    s16x8 qf1 = *(const s16x8*)(Qb + qrow + 1 * 32 + g0 * 8);

    // drel (relative-key dots) via MFMA: Krel rows 16..31 and 32
    {
        s16x8 a10 = *(const s16x8*)(Krb + (16 + qh) * 64 + 0 * 32 + g0 * 8);
        s16x8 a11 = *(const s16x8*)(Krb + (16 + qh) * 64 + 1 * 32 + g0 * 8);
        s16x8 a20 = *(const s16x8*)(Krb + (32 + qh) * 64 + 0 * 32 + g0 * 8);
        s16x8 a21 = *(const s16x8*)(Krb + (32 + qh) * 64 + 1 * 32 + g0 * 8);
        f32x4 z = {0.f, 0.f, 0.f, 0.f};
        f32x4 d1 = __builtin_amdgcn_mfma_f32_16x16x32_bf16(a10, qf0, z, 0, 0, 0);
        d1 = __builtin_amdgcn_mfma_f32_16x16x32_bf16(a11, qf1, d1, 0, 0, 0);
        f32x4 d2 = __builtin_amdgcn_mfma_f32_16x16x32_bf16(a20, qf0, z, 0, 0, 0);
        d2 = __builtin_amdgcn_mfma_f32_16x16x32_bf16(a21, qf1, d2, 0, 0, 0);
        float* drel = (float*)(lds + LDS_DREL) + wv * 320 + qh * 20;
        drel[4 * g0 + 0] = d1.x; drel[4 * g0 + 1] = d1.y;
        drel[4 * g0 + 2] = d1.z; drel[4 * g0 + 3] = d1.w;
        if (g0 == 0) drel[16] = d2.x;     // drel[q][32]
    }
    asm volatile("" ::: "memory");        // order drel writes vs reads below
    const float* drelT = (const float*)(lds + LDS_DREL) + wv * 320 + qh * 20;
    float bias32 = drelT[16];             // same-wave LDS readback

    // Vrel rows 0..16 staged f32 (stride 72 -> 16B-aligned rows)
    {
        float* vr = (float*)(lds + LDS_VREL);
        for (int i = tid; i < 17 * 16; i += 256) {
            int row = i >> 4, c4 = (i & 15) << 2;
            *(f32x4*)(vr + row * 72 + c4) = *(const f32x4*)(Vrel_g + row * 64 + c4);
        }
    }

    f32x4 o0 = {0,0,0,0}, o1 = {0,0,0,0}, o2 = {0,0,0,0}, o3 = {0,0,0,0};
    float mprev = -1e30f, lsum = 0.f;

    char* PL  = lds + LDS_P + wv * 2048;
    const int swzq = (qh & 7) << 4;
    const float* vrel = (const float*)(lds + LDS_VREL);

    // --- staging address precompute (2 rows per thread for K and VT each) ---
    const int idx0 = tid,        idx1 = tid + 256;
    const int row0 = idx0 >> 3,  cb0 = (idx0 & 7) << 4;
    const int row1 = idx1 >> 3,  cb1 = (idx1 & 7) << 4;
    const int sw0 = cb0 ^ ((row0 & 7) << 4);
    const int sw1 = cb1 ^ ((row1 & 7) << 4);
    const char* ksrc0 = (const char*)(Kb  + (size_t)(b * 2048 + row0) * 64) + cb0;
    const char* ksrc1 = (const char*)(Kb  + (size_t)(b * 2048 + row1) * 64) + cb1;
    const char* vsrc0 = (const char*)(VTb + (size_t)(b * 64 + row0) * 2048) + cb0;
    const char* vsrc1 = (const char*)(VTb + (size_t)(b * 64 + row1) * 2048) + cb1;

    s16x8 rk0, rk1, rv0, rv1;
#define LOADREGS(KT)                                                          \
    do {                                                                      \
        rk0 = *(const s16x8*)(ksrc0 + (size_t)(KT) * 8192);                   \
        rk1 = *(const s16x8*)(ksrc1 + (size_t)(KT) * 8192);                   \
        rv0 = *(const s16x8*)(vsrc0 + (size_t)(KT) * 128);                    \
        rv1 = *(const s16x8*)(vsrc1 + (size_t)(KT) * 128);                    \
    } while (0)
#define STOREREGS(BASE)                                                       \
    do {                                                                      \
        *(s16x8*)((BASE) + row0 * 128 + sw0) = rk0;                           \
        *(s16x8*)((BASE) + row1 * 128 + sw1) = rk1;                           \
        *(s16x8*)((BASE) + 8192 + row0 * 128 + sw0) = rv0;                    \
        *(s16x8*)((BASE) + 8192 + row1 * 128 + sw1) = rv1;                    \
    } while (0)

    // prologue: stage first tile into buf0
    LOADREGS(ck0);
    STOREREGS(lds + LDS_BUF0);

    const int nkt = ckend - ck0;
    for (int it = 0; it < nkt; ++it) {
        const int kt = ck0 + it;
        const int k0 = kt << 6;
        const int cur = it & 1;
        const bool havenext = (it + 1 < nkt);
        if (havenext) LOADREGS(kt + 1);   // global loads in flight across barrier
        __syncthreads();                  // buf[cur] fully staged by all waves

        char* KsL = lds + (cur ? LDS_BUF1 : LDS_BUF0);
        char* VtL = KsL + 8192;

        if (k0 <= q0w + 15) {
            // ---- S^T = K_tile . Q^T  (4 chunks of 16 keys, d split 2x32) ----
            f32x4 s0, s1, s2, s3;
            {
                f32x4 z = {0,0,0,0};
                const int b0 = (16 * g0) ^ swzq;
                const int b1 = (64 + 16 * g0) ^ swzq;
                s16x8 a00 = *(const s16x8*)(KsL + (0  + qh) * 128 + b0);
                s16x8 a01 = *(const s16x8*)(KsL + (0  + qh) * 128 + b1);
                s16x8 a10 = *(const s16x8*)(KsL + (16 + qh) * 128 + b0);
                s16x8 a11 = *(const s16x8*)(KsL + (16 + qh) * 128 + b1);
                s16x8 a20 = *(const s16x8*)(KsL + (32 + qh) * 128 + b0);
                s16x8 a21 = *(const s16x8*)(KsL + (32 + qh) * 128 + b1);
                s16x8 a30 = *(const s16x8*)(KsL + (48 + qh) * 128 + b0);
                s16x8 a31 = *(const s16x8*)(KsL + (48 + qh) * 128 + b1);
                s0 = __builtin_amdgcn_mfma_f32_16x16x32_bf16(a00, qf0, z, 0, 0, 0);
                s0 = __builtin_amdgcn_mfma_f32_16x16x32_bf16(a01, qf1, s0, 0, 0, 0);
                s1 = __builtin_amdgcn_mfma_f32_16x16x32_bf16(a10, qf0, z, 0, 0, 0);
                s1 = __builtin_amdgcn_mfma_f32_16x16x32_bf16(a11, qf1, s1, 0, 0, 0);
                s2 = __builtin_amdgcn_mfma_f32_16x16x32_bf16(a20, qf0, z, 0, 0, 0);
                s2 = __builtin_amdgcn_mfma_f32_16x16x32_bf16(a21, qf1, s2, 0, 0, 0);
                s3 = __builtin_amdgcn_mfma_f32_16x16x32_bf16(a30, qf0, z, 0, 0, 0);
                s3 = __builtin_amdgcn_mfma_f32_16x16x32_bf16(a31, qf1, s3, 0, 0, 0);
            }
            // ---- bias + mask penalty ----
            const float* penb = pen + b * 2048 + k0 + 4 * g0;
            f32x4 pn0 = *(const f32x4*)(penb + 0);
            f32x4 pn1 = *(const f32x4*)(penb + 16);
            f32x4 pn2 = *(const f32x4*)(penb + 32);
            f32x4 pn3 = *(const f32x4*)(penb + 48);
            const bool near = (k0 + 79 >= q0w);
            if (!near) {
                s0 += pn0 + bias32; s1 += pn1 + bias32;
                s2 += pn2 + bias32; s3 += pn3 + bias32;
            } else {
                near_bias(s0, pn0, 0, k0, g0, q, drelT);
                near_bias(s1, pn1, 1, k0, g0, q, drelT);
                near_bias(s2, pn2, 2, k0, g0, q, drelT);
                near_bias(s3, pn3, 3, k0, g0, q, drelT);
            }
            // ---- online softmax, log2 domain ----
            float mt = fmaxf(fmaxf(fmaxf(s0.x, s0.y), fmaxf(s0.z, s0.w)),
                      fmaxf(fmaxf(fmaxf(s1.x, s1.y), fmaxf(s1.z, s1.w)),
                      fmaxf(fmaxf(fmaxf(s2.x, s2.y), fmaxf(s2.z, s2.w)),
                            fmaxf(fmaxf(s3.x, s3.y), fmaxf(s3.z, s3.w)))));
            mt = fmaxf(mt, __shfl_xor(mt, 16));
            mt = fmaxf(mt, __shfl_xor(mt, 32));
            float mnew = fmaxf(mprev, mt);
            float fsc = __builtin_amdgcn_exp2f(mprev - mnew);
            s0.x = __builtin_amdgcn_exp2f(s0.x - mnew); s0.y = __builtin_amdgcn_exp2f(s0.y - mnew);
            s0.z = __builtin_amdgcn_exp2f(s0.z - mnew); s0.w = __builtin_amdgcn_exp2f(s0.w - mnew);
            s1.x = __builtin_amdgcn_exp2f(s1.x - mnew); s1.y = __builtin_amdgcn_exp2f(s1.y - mnew);
            s1.z = __builtin_amdgcn_exp2f(s1.z - mnew); s1.w = __builtin_amdgcn_exp2f(s1.w - mnew);
            s2.x = __builtin_amdgcn_exp2f(s2.x - mnew); s2.y = __builtin_amdgcn_exp2f(s2.y - mnew);
            s2.z = __builtin_amdgcn_exp2f(s2.z - mnew); s2.w = __builtin_amdgcn_exp2f(s2.w - mnew);
            s3.x = __builtin_amdgcn_exp2f(s3.x - mnew); s3.y = __builtin_amdgcn_exp2f(s3.y - mnew);
            s3.z = __builtin_amdgcn_exp2f(s3.z - mnew); s3.w = __builtin_amdgcn_exp2f(s3.w - mnew);
            float rs = (s0.x + s0.y + s0.z + s0.w) + (s1.x + s1.y + s1.z + s1.w)
                     + (s2.x + s2.y + s2.z + s2.w) + (s3.x + s3.y + s3.z + s3.w);
            rs += __shfl_xor(rs, 16);
            rs += __shfl_xor(rs, 32);
            lsum = lsum * fsc + rs;
            mprev = mnew;
            o0 *= fsc; o1 *= fsc; o2 *= fsc; o3 *= fsc;

            // ---- P -> bf16 -> per-wave LDS (swizzled, short-typed stores) ----
            {
                s16x4 pk;
                pk.x = (short)f2bf(s0.x); pk.y = (short)f2bf(s0.y);
                pk.z = (short)f2bf(s0.z); pk.w = (short)f2bf(s0.w);
                *(s16x4*)(PL + qh * 128 + ((0  + 8 * g0) ^ swzq)) = pk;
                pk.x = (short)f2bf(s1.x); pk.y = (short)f2bf(s1.y);
                pk.z = (short)f2bf(s1.z); pk.w = (short)f2bf(s1.w);
                *(s16x4*)(PL + qh * 128 + ((32 + 8 * g0) ^ swzq)) = pk;
                pk.x = (short)f2bf(s2.x); pk.y = (short)f2bf(s2.y);
                pk.z = (short)f2bf(s2.z); pk.w = (short)f2bf(s2.w);
                *(s16x4*)(PL + qh * 128 + ((64 + 8 * g0) ^ swzq)) = pk;
                pk.x = (short)f2bf(s3.x); pk.y = (short)f2bf(s3.y);
                pk.z = (short)f2bf(s3.z); pk.w = (short)f2bf(s3.w);
                *(s16x4*)(PL + qh * 128 + ((96 + 8 * g0) ^ swzq)) = pk;
            }
            asm volatile("" ::: "memory");   // P stores precede P reads
            // ---- O^T += V^T . P^T ----
            {
                const int b0 = (16 * g0) ^ swzq;
                const int b1 = (64 + 16 * g0) ^ swzq;
                s16x8 bP0 = *(const s16x8*)(PL + qh * 128 + b0);
                s16x8 bP1 = *(const s16x8*)(PL + qh * 128 + b1);
                asm volatile("" ::: "memory");
                s16x8 v00 = *(const s16x8*)(VtL + (0  + qh) * 128 + b0);
                s16x8 v01 = *(const s16x8*)(VtL + (0  + qh) * 128 + b1);
                s16x8 v10 = *(const s16x8*)(VtL + (16 + qh) * 128 + b0);
                s16x8 v11 = *(const s16x8*)(VtL + (16 + qh) * 128 + b1);
                s16x8 v20 = *(const s16x8*)(VtL + (32 + qh) * 128 + b0);
                s16x8 v21 = *(const s16x8*)(VtL + (32 + qh) * 128 + b1);
                s16x8 v30 = *(const s16x8*)(VtL + (48 + qh) * 128 + b0);
                s16x8 v31 = *(const s16x8*)(VtL + (48 + qh) * 128 + b1);
                o0 = __builtin_amdgcn_mfma_f32_16x16x32_bf16(v00, bP0, o0, 0, 0, 0);
                o0 = __builtin_amdgcn_mfma_f32_16x16x32_bf16(v01, bP1, o0, 0, 0, 0);
                o1 = __builtin_amdgcn_mfma_f32_16x16x32_bf16(v10, bP0, o1, 0, 0, 0);
                o1 = __builtin_amdgcn_mfma_f32_16x16x32_bf16(v11, bP1, o1, 0, 0, 0);
                o2 = __builtin_amdgcn_mfma_f32_16x16x32_bf16(v20, bP0, o2, 0, 0, 0);
                o2 = __builtin_amdgcn_mfma_f32_16x16x32_bf16(v21, bP1, o2, 0, 0, 0);
                o3 = __builtin_amdgcn_mfma_f32_16x16x32_bf16(v30, bP0, o3, 0, 0, 0);
                o3 = __builtin_amdgcn_mfma_f32_16x16x32_bf16(v31, bP1, o3, 0, 0, 0);
            }
            // ---- near-diagonal relative-value recombination (all d) ----
            if (near) {
                const int kql = q - k0;
                #pragma unroll
                for (int dlt = 0; dlt <= 16; ++dlt) {
                    int kkl = kql - dlt;
                    if (kkl >= 0 && kkl < 64) {
                        float p = bf2f(*(const unsigned short*)
                                       (PL + qh * 128 + ((2 * kkl) ^ swzq)));
                        const float* vrow = vrel + (16 - dlt) * 72 + 4 * g0;
                        o0 += p * *(const f32x4*)(vrow + 0);
                        o1 += p * *(const f32x4*)(vrow + 16);
                        o2 += p * *(const f32x4*)(vrow + 32);
                        o3 += p * *(const f32x4*)(vrow + 48);
                    }
                }
            }
        }

        // stage next tile into the other buffer (safe: last read of that
        // buffer was iteration it-1, all waves passed this iter's barrier)
        if (havenext) {
            STOREREGS(lds + ((cur ^ 1) ? LDS_BUF1 : LDS_BUF0));
        }
    }

    // ---- epilogue ----
    if (is_final) {
        float inv = 1.f / lsum;
        float* op = Out + (size_t)(b * 2048 + q) * 64 + 4 * g0;
        *(f32x4*)(op + 0)  = o0 * inv;
        *(f32x4*)(op + 16) = o1 * inv;
        *(f32x4*)(op + 32) = o2 * inv;
        *(f32x4*)(op + 48) = o3 * inv;
    } else {
        float* op = (float*)(ws + OFF_OPART) + (size_t)u * 4096 + (wv * 16 + qh) * 64 + 4 * g0;
        *(f32x4*)(op + 0)  = o0;
        *(f32x4*)(op + 16) = o1;
        *(f32x4*)(op + 32) = o2;
        *(f32x4*)(op + 48) = o3;
        if (g0 == 0) {
            float* ml = (float*)(ws + OFF_ML) + (size_t)u * 128 + (wv * 16 + qh) * 2;
            ml[0] = mprev; ml[1] = lsum;
        }
    }
}

// ---------------- split-K combine ----------------
__global__ __launch_bounds__(256)
void combine_kernel(float* __restrict__ Out, const char* __restrict__ ws)
{
    int bid = blockIdx.x;          // 192 = 8 batches x 24 q-tiles (t=8..31)
    int b = bid / 24;
    int t = 8 + bid % 24;
    int nck = t / 8 + 1;
    int S;
    if (t < 16)      S = 8 + 2 * (t - 8);
    else if (t < 24) S = 24 + 3 * (t - 16);
    else             S = 48 + 4 * (t - 24);
    int ubase = b * UPB + S;
    int tid = threadIdx.x;
    int qloc = tid >> 2;
    int d0 = (tid & 3) << 4;
    const float* mlb = (const float*)(ws + OFF_ML);
    const float* opb = (const float*)(ws + OFF_OPART);

    float m[4], l[4];
    float M = -1e30f;
    #pragma unroll
    for (int i = 0; i < 4; ++i) {
        if (i < nck) {
            const float* ml = mlb + (size_t)(ubase + i) * 128 + qloc * 2;
            m[i] = ml[0]; l[i] = ml[1];
            M = fmaxf(M, m[i]);
        }
    }
    float L = 0.f;
    float coef[4];
    #pragma unroll
    for (int i = 0; i < 4; ++i) {
        if (i < nck) { coef[i] = __builtin_amdgcn_exp2f(m[i] - M); L += l[i] * coef[i]; }
    }
    f32x4 a0 = {0,0,0,0}, a1 = {0,0,0,0}, a2 = {0,0,0,0}, a3 = {0,0,0,0};
    #pragma unroll
    for (int i = 0; i < 4; ++i) {
        if (i < nck) {
            const float* op = opb + (size_t)(ubase + i) * 4096 + qloc * 64 + d0;
            a0 += coef[i] * *(const f32x4*)(op + 0);
            a1 += coef[i] * *(const f32x4*)(op + 4);
            a2 += coef[i] * *(const f32x4*)(op + 8);
            a3 += coef[i] * *(const f32x4*)(op + 12);
        }
    }
    float inv = 1.f / L;
    float* oo = Out + (size_t)(b * 2048 + t * 64 + qloc) * 64 + d0;
    *(f32x4*)(oo + 0)  = a0 * inv;
    *(f32x4*)(oo + 4)  = a1 * inv;
    *(f32x4*)(oo + 8)  = a2 * inv;
    *(f32x4*)(oo + 12) = a3 * inv;
}

extern "C" void kernel_launch(void* const* d_in, const int* in_sizes, int n_in,
                              void* d_out, int out_size, void* d_ws, size_t ws_size,
                              hipStream_t stream) {
    (void)in_sizes; (void)n_in; (void)out_size; (void)ws_size;
    const float* Q    = (const float*)d_in[0];
    const float* K    = (const float*)d_in[1];
    const float* V    = (const float*)d_in[2];
    const float* Msk  = (const float*)d_in[3];
    const float* Krel = (const float*)d_in[4];
    const float* Vrel = (const float*)d_in[5];
    float* Out = (float*)d_out;
    char* ws = (char*)d_ws;

    convert_kernel<<<2313, 256, 0, stream>>>(Q, K, V, Msk, Krel, ws);
    attn_main<<<NUNIT, 256, 0, stream>>>(Vrel, Out, ws);
    combine_kernel<<<192, 256, 0, stream>>>(Out, ws);
}